// Round 7
// baseline (157.337 us; speedup 1.0000x reference)
//
#include <hip/hip_runtime.h>
#include <stdint.h>

#define N_ROWS 4096
#define DIM    1024
#define NCLS   64
#define EPSV   0.1f

typedef __attribute__((ext_vector_type(4))) float f32x4;
typedef __attribute__((ext_vector_type(8))) int   i32x8;

__device__ __forceinline__ float softplus(float x) {
    return fmaxf(x, 0.f) + __logf(1.f + __expf(-fabsf(x)));
}

// ---------------- K1: per-class sum/sqsum via row gather (unchanged) ---------
__global__ __launch_bounds__(256) void k_cstats(const float* __restrict__ X,
                                                const int* __restrict__ tgt,
                                                float* __restrict__ csumR,
                                                float* __restrict__ csqR) {
    __shared__ int rows[N_ROWS];
    __shared__ int nrows_s;
    int tid = threadIdx.x;
    int c = blockIdx.x >> 2, q = blockIdx.x & 3;
    if (tid == 0) nrows_s = 0;
    __syncthreads();
    for (int i = tid; i < N_ROWS; i += 256)
        if (tgt[i] == c) { int p = atomicAdd(&nrows_s, 1); rows[p] = i; }
    __syncthreads();
    int n = nrows_s;
    int d = q * 256 + tid;
    float s = 0.f, qq = 0.f;
    #pragma unroll 4
    for (int r = 0; r < n; r++) {
        float x = X[(size_t)rows[r] * DIM + d];
        s += x; qq += x * x;
    }
    csumR[c * DIM + d] = s;
    csqR [c * DIM + d] = qq;
}

// ---------------- K2: counts + weights + fp8 scale + zero loss (unchanged) ---
__global__ __launch_bounds__(128) void k_weights(const int* __restrict__ tgt,
                                                 const float* __restrict__ csumR,
                                                 const float* __restrict__ csqR,
                                                 float* __restrict__ w,
                                                 float* __restrict__ scal,
                                                 float* __restrict__ loss_out) {
    __shared__ int hist[NCLS];
    __shared__ float redw[2];
    int tid = threadIdx.x, b = blockIdx.x;
    if (tid < NCLS) hist[tid] = 0;
    __syncthreads();
    for (int i = tid; i < N_ROWS; i += 128) atomicAdd(&hist[tgt[i]], 1);
    __syncthreads();
    long long sp = 0, ss = 0;
    for (int c = 0; c < NCLS; c++) { long long cc = hist[c]; sp += cc * (cc - 1); ss += cc * cc; }
    float cnt_pos = (float)sp;
    float cnt_neg = (float)((long long)N_ROWS * N_ROWS - ss);
    int d = b * 128 + tid;
    float A = 0.f, X2 = 0.f, T = 0.f, SS = 0.f;
    #pragma unroll 8
    for (int c = 0; c < NCLS; c++) {
        float s = csumR[c * DIM + d];
        float q = csqR [c * DIM + d];
        A += (float)hist[c] * q; X2 += q; T += s; SS += s * s;
    }
    float posnum = 2.f * (A - SS);
    float negnum = 2.f * ((float)N_ROWS * X2 - A - T * T + SS);
    float wd = cnt_neg / (negnum + EPSV) - cnt_pos / (posnum + EPSV);
    w[d] = wd;
    float m = wd * wd;
    for (int off = 32; off; off >>= 1) m += __shfl_down(m, off, 64);
    int wv = tid >> 6, ln = tid & 63;
    if (ln == 0) redw[wv] = m;
    __syncthreads();
    if (b == 0 && tid == 0) {
        float ms = (redw[0] + redw[1]) / 128.f;
        scal[0] = exp2f(roundf(log2f(sqrtf(ms) + 1e-30f)));
        loss_out[0] = 0.0f;
    }
}

// ---------------- K3: xw, sq, fp8 casts -> FRAGMENT-MAJOR global layout ------
// Layout (uint index): panel p = row>>7 (128-row panel), r = row&127,
// fb = r>>4 (16-row frag block), lr = r&15, step = d>>7 (128-dim K-step),
// chunk = (d&127)>>5 (32B K-chunk, 0..3), u8 = (d&31)>>2 (uint in chunk).
// uidx = p*32768 + step*4096 + fb*512 + chunk*128 + lr*8 + u8
// => gemm lane l of fragment (panel, step, fb) reads its 32 B at
// fb*512 + (l>>4)*128 + (l&15)*8: contiguous, coalesced, K-ordered.
// R6 BUG (fixed): used hk=(d>>4)&7 (16B granule) * 128 + (d>>2&3) -> offsets
// overflowed the 512-uint fragment and collided across fb (128*(4*fb+hk)
// non-injective) -> rows mixed, absmax 0.086.
__global__ __launch_bounds__(256) void k_prep(const float* __restrict__ X,
                                              const float* __restrict__ w,
                                              const float* __restrict__ scal,
                                              unsigned int* __restrict__ Xb8,
                                              unsigned int* __restrict__ XWb8,
                                              float* __restrict__ sq) {
    int row = blockIdx.x, tid = threadIdx.x;
    float inv_sw = 1.0f / scal[0];
    float4 x  = ((const float4*)(X + (size_t)row * DIM))[tid];
    float4 ww = ((const float4*)w)[tid];
    float4 xw = make_float4(x.x * ww.x, x.y * ww.y, x.z * ww.z, x.w * ww.w);
    float p = x.x * xw.x + x.y * xw.y + x.z * xw.z + x.w * xw.w;
    unsigned ux = __builtin_amdgcn_cvt_pk_fp8_f32(x.x, x.y, 0, false);
    ux = __builtin_amdgcn_cvt_pk_fp8_f32(x.z, x.w, ux, true);
    unsigned uw = __builtin_amdgcn_cvt_pk_fp8_f32(xw.x * inv_sw, xw.y * inv_sw, 0, false);
    uw = __builtin_amdgcn_cvt_pk_fp8_f32(xw.z * inv_sw, xw.w * inv_sw, uw, true);
    int pnl = row >> 7, r = row & 127;
    int fb = r >> 4, lr = r & 15;
    int step = tid >> 5, chunk = (tid >> 3) & 3, u8 = tid & 7;
    int uidx = pnl * 32768 + step * 4096 + fb * 512 + chunk * 128 + lr * 8 + u8;
    Xb8 [uidx] = ux;
    XWb8[uidx] = uw;
    for (int off = 32; off; off >>= 1) p += __shfl_down(p, off, 64);
    __shared__ float red[4];
    int wv = tid >> 6, ln = tid & 63;
    if (ln == 0) red[wv] = p;
    __syncthreads();
    if (tid == 0) sq[row] = red[0] + red[1] + red[2] + red[3];
}

// ---------------- K4: LDS-free MX-fp8 MFMA gram + softplus + masked mean -----
// The fp8 operand buffers are 8.4 MB = L3-resident and k_prep owns their
// layout -> fragment-major storage lets MFMA operands load DIRECTLY from
// global (i32x8 = 2x global_load_dwordx4, wave-contiguous 2 KB per frag).
// No K-loop LDS, no barriers, no swizzles; compiler pipelines loads freely.
// 256 thr = 4 waves (2x2), wave tile 64x64 (4x4 frags of 16x16x128).
// Blocks with equal g=blockIdx&7 share jt panels on one XCD (round-robin)
// -> B panels L2-resident; A panels served by L3.
__global__ __launch_bounds__(256) void k_gemm_loss(const unsigned int* __restrict__ Xb8,
                                                   const unsigned int* __restrict__ XWb8,
                                                   const float* __restrict__ sq,
                                                   const int* __restrict__ tgt,
                                                   const float* __restrict__ scal,
                                                   float* __restrict__ loss) {
    __shared__ float sqI[128], sqJ[128];
    __shared__ int   tIs[128], tJs[128];
    __shared__ float red[4];

    int tid = threadIdx.x;
    int wave = tid >> 6, lane = tid & 63;

    // balanced triangular decode (32x32 tile grid, 528 tiles)
    int g = blockIdx.x & 7, s = blockIdx.x >> 3;
    int j0 = g, j1 = 15 - g, j2 = 16 + g;
    int n0 = j0 + 1, n1 = j1 + 1, n2 = j2 + 1;
    int jt, it;
    if      (s < n0)           { jt = j0; it = s; }
    else if (s < n0 + n1)      { jt = j1; it = s - n0; }
    else if (s < n0 + n1 + n2) { jt = j2; it = s - n0 - n1; }
    else                       { jt = 31 - g; it = s - n0 - n1 - n2; }

    int lr = lane & 15, hk = lane >> 4;
    int wrow = (wave >> 1) * 64, wcol = (wave & 1) * 64;

    // fragment base pointers (uints); per-step stride = 4096 uints (16 KB)
    const unsigned int* pa[4];
    const unsigned int* pb[4];
    #pragma unroll
    for (int mi = 0; mi < 4; mi++) {
        int fb = (wrow >> 4) + mi;
        pa[mi] = Xb8 + (size_t)it * 32768 + fb * 512 + hk * 128 + lr * 8;
    }
    #pragma unroll
    for (int nj = 0; nj < 4; nj++) {
        int fb = (wcol >> 4) + nj;
        pb[nj] = XWb8 + (size_t)jt * 32768 + fb * 512 + hk * 128 + lr * 8;
    }

    f32x4 acc[4][4];
    #pragma unroll
    for (int i = 0; i < 4; i++)
        #pragma unroll
        for (int j = 0; j < 4; j++) acc[i][j] = (f32x4){0.f, 0.f, 0.f, 0.f};

    #pragma unroll
    for (int st = 0; st < 8; st++) {
        i32x8 av[4], bv[4];
        #pragma unroll
        for (int mi = 0; mi < 4; mi++) av[mi] = *(const i32x8*)(pa[mi] + st * 4096);
        #pragma unroll
        for (int nj = 0; nj < 4; nj++) bv[nj] = *(const i32x8*)(pb[nj] + st * 4096);
        #pragma unroll
        for (int mi = 0; mi < 4; mi++)
            #pragma unroll
            for (int nj = 0; nj < 4; nj++)
                acc[mi][nj] = __builtin_amdgcn_mfma_scale_f32_16x16x128_f8f6f4(
                    av[mi], bv[nj], acc[mi][nj], 0, 0, 0, 127, 0, 127);
    }

    // epilogue: S = sq_i + sq_j - 2*sw*G', masked softplus, x2 off-diagonal
    if (tid < 128)      { sqI[tid] = sq[it * 128 + tid]; tIs[tid] = tgt[it * 128 + tid]; }
    else                { int u = tid - 128; sqJ[u] = sq[jt * 128 + u]; tJs[u] = tgt[jt * 128 + u]; }
    __syncthreads();

    float sw2 = 2.0f * scal[0];
    float sum = 0.f;
    bool diagTile = (it == jt);
    #pragma unroll
    for (int j = 0; j < 4; j++) {
        int col = wcol + j * 16 + (lane & 15);            // C/D: col = lane&15
        float sj = sqJ[col]; int tj = tJs[col];
        #pragma unroll
        for (int i = 0; i < 4; i++) {
            int rbase = wrow + i * 16 + (lane >> 4) * 4;  // C/D: row = quad*4+reg
            #pragma unroll
            for (int rr = 0; rr < 4; rr++) {
                int rowp = rbase + rr;
                float S = sqI[rowp] + sj - sw2 * acc[i][j][rr];
                float v;
                if (tIs[rowp] == tj) v = (diagTile && rowp == col) ? 0.f : softplus(-S);
                else                 v = softplus(S);
                sum += v;
            }
        }
    }
    float scale = (diagTile ? 1.f : 2.f) * (1.f / ((float)N_ROWS * (float)(N_ROWS - 1)));
    sum *= scale;
    for (int off = 32; off; off >>= 1) sum += __shfl_down(sum, off, 64);
    if (lane == 0) red[wave] = sum;
    __syncthreads();
    if (tid == 0) {
        float t = red[0] + red[1] + red[2] + red[3];
        atomicAdd(loss, t);
    }
}

extern "C" void kernel_launch(void* const* d_in, const int* in_sizes, int n_in,
                              void* d_out, int out_size, void* d_ws, size_t ws_size,
                              hipStream_t stream) {
    const float* X  = (const float*)d_in[0];
    const int* tgt  = (const int*)d_in[1];
    float* out = (float*)d_out;
    char* ws = (char*)d_ws;
    const size_t MB = 1u << 20;

    float* w      = (float*)ws;                         // 4 KB
    float* sq     = (float*)(ws + 4096);                // 16 KB
    float* scal   = (float*)(ws + 24576);               // 4 B
    unsigned int* Xb8  = (unsigned int*)(ws + 1 * MB);  // 4 MB (fragment-major)
    unsigned int* XWb8 = (unsigned int*)(ws + 5 * MB);  // 4 MB (fragment-major)
    float* csumR  = (float*)(ws + 9 * MB);              // 256 KB
    float* csqR   = (float*)(ws + 9 * MB + 256 * 1024); // 256 KB

    k_cstats  <<<256,  256, 0, stream>>>(X, tgt, csumR, csqR);
    k_weights <<<8,    128, 0, stream>>>(tgt, csumR, csqR, w, scal, out);
    k_prep    <<<4096, 256, 0, stream>>>(X, w, scal, Xb8, XWb8, sq);
    k_gemm_loss<<<528, 256, 0, stream>>>(Xb8, XWb8, sq, tgt, scal, out);
}

// Round 8
// 127.180 us; speedup vs baseline: 1.2371x; 1.2371x over previous
//
#include <hip/hip_runtime.h>
#include <stdint.h>

#define N_ROWS 4096
#define DIM    1024
#define NCLS   64
#define EPSV   0.1f

typedef __attribute__((ext_vector_type(4))) float f32x4;
typedef __attribute__((ext_vector_type(8))) int   i32x8;

__device__ __forceinline__ float softplus(float x) {
    return fmaxf(x, 0.f) + __logf(1.f + __expf(-fabsf(x)));
}

// ---------------- K1: per-class sum/sqsum via row gather (unchanged) ---------
__global__ __launch_bounds__(256) void k_cstats(const float* __restrict__ X,
                                                const int* __restrict__ tgt,
                                                float* __restrict__ csumR,
                                                float* __restrict__ csqR) {
    __shared__ int rows[N_ROWS];
    __shared__ int nrows_s;
    int tid = threadIdx.x;
    int c = blockIdx.x >> 2, q = blockIdx.x & 3;
    if (tid == 0) nrows_s = 0;
    __syncthreads();
    for (int i = tid; i < N_ROWS; i += 256)
        if (tgt[i] == c) { int p = atomicAdd(&nrows_s, 1); rows[p] = i; }
    __syncthreads();
    int n = nrows_s;
    int d = q * 256 + tid;
    float s = 0.f, qq = 0.f;
    #pragma unroll 4
    for (int r = 0; r < n; r++) {
        float x = X[(size_t)rows[r] * DIM + d];
        s += x; qq += x * x;
    }
    csumR[c * DIM + d] = s;
    csqR [c * DIM + d] = qq;
}

// ---------------- K2: counts + weights + fp8 scale + zero loss (unchanged) ---
__global__ __launch_bounds__(128) void k_weights(const int* __restrict__ tgt,
                                                 const float* __restrict__ csumR,
                                                 const float* __restrict__ csqR,
                                                 float* __restrict__ w,
                                                 float* __restrict__ scal,
                                                 float* __restrict__ loss_out) {
    __shared__ int hist[NCLS];
    __shared__ float redw[2];
    int tid = threadIdx.x, b = blockIdx.x;
    if (tid < NCLS) hist[tid] = 0;
    __syncthreads();
    for (int i = tid; i < N_ROWS; i += 128) atomicAdd(&hist[tgt[i]], 1);
    __syncthreads();
    long long sp = 0, ss = 0;
    for (int c = 0; c < NCLS; c++) { long long cc = hist[c]; sp += cc * (cc - 1); ss += cc * cc; }
    float cnt_pos = (float)sp;
    float cnt_neg = (float)((long long)N_ROWS * N_ROWS - ss);
    int d = b * 128 + tid;
    float A = 0.f, X2 = 0.f, T = 0.f, SS = 0.f;
    #pragma unroll 8
    for (int c = 0; c < NCLS; c++) {
        float s = csumR[c * DIM + d];
        float q = csqR [c * DIM + d];
        A += (float)hist[c] * q; X2 += q; T += s; SS += s * s;
    }
    float posnum = 2.f * (A - SS);
    float negnum = 2.f * ((float)N_ROWS * X2 - A - T * T + SS);
    float wd = cnt_neg / (negnum + EPSV) - cnt_pos / (posnum + EPSV);
    w[d] = wd;
    float m = wd * wd;
    for (int off = 32; off; off >>= 1) m += __shfl_down(m, off, 64);
    int wv = tid >> 6, ln = tid & 63;
    if (ln == 0) redw[wv] = m;
    __syncthreads();
    if (b == 0 && tid == 0) {
        float ms = (redw[0] + redw[1]) / 128.f;
        scal[0] = exp2f(roundf(log2f(sqrtf(ms) + 1e-30f)));
        loss_out[0] = 0.0f;
    }
}

// ---------------- K3: xw, sq, fp8 casts -> FRAGMENT-MAJOR global layout ------
// uidx = pnl*32768 + step*4096 + fb*512 + chunk*128 + lr*8 + u8
// (verified bijective in R7: absmax = 0.0)
__global__ __launch_bounds__(256) void k_prep(const float* __restrict__ X,
                                              const float* __restrict__ w,
                                              const float* __restrict__ scal,
                                              unsigned int* __restrict__ Xb8,
                                              unsigned int* __restrict__ XWb8,
                                              float* __restrict__ sq) {
    int row = blockIdx.x, tid = threadIdx.x;
    float inv_sw = 1.0f / scal[0];
    float4 x  = ((const float4*)(X + (size_t)row * DIM))[tid];
    float4 ww = ((const float4*)w)[tid];
    float4 xw = make_float4(x.x * ww.x, x.y * ww.y, x.z * ww.z, x.w * ww.w);
    float p = x.x * xw.x + x.y * xw.y + x.z * xw.z + x.w * xw.w;
    unsigned ux = __builtin_amdgcn_cvt_pk_fp8_f32(x.x, x.y, 0, false);
    ux = __builtin_amdgcn_cvt_pk_fp8_f32(x.z, x.w, ux, true);
    unsigned uw = __builtin_amdgcn_cvt_pk_fp8_f32(xw.x * inv_sw, xw.y * inv_sw, 0, false);
    uw = __builtin_amdgcn_cvt_pk_fp8_f32(xw.z * inv_sw, xw.w * inv_sw, uw, true);
    int pnl = row >> 7, r = row & 127;
    int fb = r >> 4, lr = r & 15;
    int step = tid >> 5, chunk = (tid >> 3) & 3, u8 = tid & 7;
    int uidx = pnl * 32768 + step * 4096 + fb * 512 + chunk * 128 + lr * 8 + u8;
    Xb8 [uidx] = ux;
    XWb8[uidx] = uw;
    for (int off = 32; off; off >>= 1) p += __shfl_down(p, off, 64);
    __shared__ float red[4];
    int wv = tid >> 6, ln = tid & 63;
    if (ln == 0) red[wv] = p;
    __syncthreads();
    if (tid == 0) sq[row] = red[0] + red[1] + red[2] + red[3];
}

// ---------------- K4: LDS-free MX-fp8 MFMA gram + softplus + masked mean -----
// R7 post-mortem: full `#pragma unroll` on the K-loop let the scheduler hoist
// operand loads across all 8 steps -> demand >> 256 VGPR -> 59 MB scratch
// (437 B/thread), VGPR pinned at 256. The layout itself is verified correct
// (absmax 0.0, bank-conflict 0, FETCH 54 MB = L2/L3-served panels).
// FIX: `#pragma unroll 1` bounds the window to one K-step, and the per-step
// footprint is trimmed: bv0..3 (32 regs, named scalars per rule #20) loaded
// once per step; av (8 regs) loaded per-mi. Peak live ~ acc 64 + bv 32 +
// av 8+8 + ptrs ~20 = ~135-160 VGPR -> no spill, ~3 waves/SIMD to hide
// L2/L3 operand latency.
__global__ __launch_bounds__(256) void k_gemm_loss(const unsigned int* __restrict__ Xb8,
                                                   const unsigned int* __restrict__ XWb8,
                                                   const float* __restrict__ sq,
                                                   const int* __restrict__ tgt,
                                                   const float* __restrict__ scal,
                                                   float* __restrict__ loss) {
    __shared__ float sqI[128], sqJ[128];
    __shared__ int   tIs[128], tJs[128];
    __shared__ float red[4];

    int tid = threadIdx.x;
    int wave = tid >> 6, lane = tid & 63;

    // balanced triangular decode (32x32 tile grid, 528 tiles)
    int g = blockIdx.x & 7, s = blockIdx.x >> 3;
    int j0 = g, j1 = 15 - g, j2 = 16 + g;
    int n0 = j0 + 1, n1 = j1 + 1, n2 = j2 + 1;
    int jt, it;
    if      (s < n0)           { jt = j0; it = s; }
    else if (s < n0 + n1)      { jt = j1; it = s - n0; }
    else if (s < n0 + n1 + n2) { jt = j2; it = s - n0 - n1; }
    else                       { jt = 31 - g; it = s - n0 - n1 - n2; }

    int lr = lane & 15, hk = lane >> 4;
    int wrow = (wave >> 1) * 64, wcol = (wave & 1) * 64;

    // fragment base pointers (uints); per-step stride = 4096 uints (16 KB)
    const unsigned int* pa[4];
    const unsigned int* pb[4];
    #pragma unroll
    for (int mi = 0; mi < 4; mi++) {
        int fb = (wrow >> 4) + mi;
        pa[mi] = Xb8 + (size_t)it * 32768 + fb * 512 + hk * 128 + lr * 8;
    }
    #pragma unroll
    for (int nj = 0; nj < 4; nj++) {
        int fb = (wcol >> 4) + nj;
        pb[nj] = XWb8 + (size_t)jt * 32768 + fb * 512 + hk * 128 + lr * 8;
    }

    f32x4 acc[4][4];
    #pragma unroll
    for (int i = 0; i < 4; i++)
        #pragma unroll
        for (int j = 0; j < 4; j++) acc[i][j] = (f32x4){0.f, 0.f, 0.f, 0.f};

    #pragma unroll 1
    for (int st = 0; st < 8; st++) {
        const int so = st * 4096;
        i32x8 bv0 = *(const i32x8*)(pb[0] + so);
        i32x8 bv1 = *(const i32x8*)(pb[1] + so);
        i32x8 bv2 = *(const i32x8*)(pb[2] + so);
        i32x8 bv3 = *(const i32x8*)(pb[3] + so);
        #pragma unroll
        for (int mi = 0; mi < 4; mi++) {
            i32x8 av = *(const i32x8*)(pa[mi] + so);
            acc[mi][0] = __builtin_amdgcn_mfma_scale_f32_16x16x128_f8f6f4(
                av, bv0, acc[mi][0], 0, 0, 0, 127, 0, 127);
            acc[mi][1] = __builtin_amdgcn_mfma_scale_f32_16x16x128_f8f6f4(
                av, bv1, acc[mi][1], 0, 0, 0, 127, 0, 127);
            acc[mi][2] = __builtin_amdgcn_mfma_scale_f32_16x16x128_f8f6f4(
                av, bv2, acc[mi][2], 0, 0, 0, 127, 0, 127);
            acc[mi][3] = __builtin_amdgcn_mfma_scale_f32_16x16x128_f8f6f4(
                av, bv3, acc[mi][3], 0, 0, 0, 127, 0, 127);
        }
    }

    // epilogue: S = sq_i + sq_j - 2*sw*G', masked softplus, x2 off-diagonal
    if (tid < 128)      { sqI[tid] = sq[it * 128 + tid]; tIs[tid] = tgt[it * 128 + tid]; }
    else                { int u = tid - 128; sqJ[u] = sq[jt * 128 + u]; tJs[u] = tgt[jt * 128 + u]; }
    __syncthreads();

    float sw2 = 2.0f * scal[0];
    float sum = 0.f;
    bool diagTile = (it == jt);
    #pragma unroll
    for (int j = 0; j < 4; j++) {
        int col = wcol + j * 16 + (lane & 15);            // C/D: col = lane&15
        float sj = sqJ[col]; int tj = tJs[col];
        #pragma unroll
        for (int i = 0; i < 4; i++) {
            int rbase = wrow + i * 16 + (lane >> 4) * 4;  // C/D: row = quad*4+reg
            #pragma unroll
            for (int rr = 0; rr < 4; rr++) {
                int rowp = rbase + rr;
                float S = sqI[rowp] + sj - sw2 * acc[i][j][rr];
                float v;
                if (tIs[rowp] == tj) v = (diagTile && rowp == col) ? 0.f : softplus(-S);
                else                 v = softplus(S);
                sum += v;
            }
        }
    }
    float scale = (diagTile ? 1.f : 2.f) * (1.f / ((float)N_ROWS * (float)(N_ROWS - 1)));
    sum *= scale;
    for (int off = 32; off; off >>= 1) sum += __shfl_down(sum, off, 64);
    if (lane == 0) red[wave] = sum;
    __syncthreads();
    if (tid == 0) {
        float t = red[0] + red[1] + red[2] + red[3];
        atomicAdd(loss, t);
    }
}

extern "C" void kernel_launch(void* const* d_in, const int* in_sizes, int n_in,
                              void* d_out, int out_size, void* d_ws, size_t ws_size,
                              hipStream_t stream) {
    const float* X  = (const float*)d_in[0];
    const int* tgt  = (const int*)d_in[1];
    float* out = (float*)d_out;
    char* ws = (char*)d_ws;
    const size_t MB = 1u << 20;

    float* w      = (float*)ws;                         // 4 KB
    float* sq     = (float*)(ws + 4096);                // 16 KB
    float* scal   = (float*)(ws + 24576);               // 4 B
    unsigned int* Xb8  = (unsigned int*)(ws + 1 * MB);  // 4 MB (fragment-major)
    unsigned int* XWb8 = (unsigned int*)(ws + 5 * MB);  // 4 MB (fragment-major)
    float* csumR  = (float*)(ws + 9 * MB);              // 256 KB
    float* csqR   = (float*)(ws + 9 * MB + 256 * 1024); // 256 KB

    k_cstats  <<<256,  256, 0, stream>>>(X, tgt, csumR, csqR);
    k_weights <<<8,    128, 0, stream>>>(tgt, csumR, csqR, w, scal, out);
    k_prep    <<<4096, 256, 0, stream>>>(X, w, scal, Xb8, XWb8, sq);
    k_gemm_loss<<<528, 256, 0, stream>>>(Xb8, XWb8, sq, tgt, scal, out);
}